// Round 1
// baseline (1719.165 us; speedup 1.0000x reference)
//
#include <hip/hip_runtime.h>
#include <math.h>

#define BB 32
#define KD 4096
#define FEA 384
#define NG 196
#define NL 36
#define INV_ST 10.0f

// ws layout (float index space)
#define WS_TCLS 0                           // 64*4096 teacher cls probs
#define WS_TREG_M (WS_TCLS + 64 * 4096)     // 12544 row max of (x-cg)/T
#define WS_TREG_Z (WS_TREG_M + 12544)       // 12544 row sum-exp
#define WS_TFEA_INV (WS_TREG_Z + 12544)     // 12544 teacher fea 1/norm
#define WS_IND (WS_TFEA_INV + 12544)        // 21760*2 int argmax indices
#define WS_ACC (WS_IND + 21760 * 2)         // 64 floats: [0..19] region, [20..39] cls CE, [40..59] L1

__device__ __forceinline__ float get_invT(const int* ep) {
    int e = *ep;
    float T = (e < 30) ? (0.04f + (float)e * (0.03f / 29.0f)) : 0.07f;
    return 1.0f / T;
}

__device__ __forceinline__ float bsum(float v, volatile float* scr) {
    #pragma unroll
    for (int m = 32; m >= 1; m >>= 1) v += __shfl_xor(v, m, 64);
    __syncthreads();
    if ((threadIdx.x & 63) == 0) scr[threadIdx.x >> 6] = v;
    __syncthreads();
    return scr[0] + scr[1] + scr[2] + scr[3];
}

__device__ __forceinline__ float bmax(float v, volatile float* scr) {
    #pragma unroll
    for (int m = 32; m >= 1; m >>= 1) v = fmaxf(v, __shfl_xor(v, m, 64));
    __syncthreads();
    if ((threadIdx.x & 63) == 0) scr[threadIdx.x >> 6] = v;
    __syncthreads();
    return fmaxf(fmaxf(scr[0], scr[1]), fmaxf(scr[2], scr[3]));
}

// teacher cls softmax probs -> ws  (64 rows)
__global__ void k_tcls(const float* __restrict__ tcls, const float* __restrict__ center,
                       const int* __restrict__ ep, float* __restrict__ ws) {
    __shared__ float scr[4];
    float invT = get_invT(ep);
    int r = blockIdx.x, tid = threadIdx.x;
    const float* row = tcls + (size_t)r * KD;
    float* out = ws + WS_TCLS + (size_t)r * KD;
    float lv[16];
    float mx = -1e30f;
    #pragma unroll
    for (int j = 0; j < 4; ++j) {
        float4 x = *(const float4*)(row + j * 1024 + tid * 4);
        float4 c = *(const float4*)(center + j * 1024 + tid * 4);
        lv[j * 4 + 0] = (x.x - c.x) * invT;
        lv[j * 4 + 1] = (x.y - c.y) * invT;
        lv[j * 4 + 2] = (x.z - c.z) * invT;
        lv[j * 4 + 3] = (x.w - c.w) * invT;
        mx = fmaxf(mx, fmaxf(fmaxf(lv[j * 4 + 0], lv[j * 4 + 1]), fmaxf(lv[j * 4 + 2], lv[j * 4 + 3])));
    }
    float m = bmax(mx, scr);
    float s = 0.f;
    #pragma unroll
    for (int i = 0; i < 16; ++i) s += __expf(lv[i] - m);
    float Z = bsum(s, scr);
    float iz = 1.0f / Z;
    #pragma unroll
    for (int j = 0; j < 4; ++j) {
        float4 o;
        o.x = __expf(lv[j * 4 + 0] - m) * iz;
        o.y = __expf(lv[j * 4 + 1] - m) * iz;
        o.z = __expf(lv[j * 4 + 2] - m) * iz;
        o.w = __expf(lv[j * 4 + 3] - m) * iz;
        *(float4*)(out + j * 1024 + tid * 4) = o;
    }
}

// teacher region softmax stats (m, Z) per row  (12544 rows)
__global__ void k_treg_stats(const float* __restrict__ treg, const float* __restrict__ cg,
                             const int* __restrict__ ep, float* __restrict__ ws) {
    __shared__ float scr[4];
    float invT = get_invT(ep);
    int r = blockIdx.x, tid = threadIdx.x;
    const float* row = treg + (size_t)r * KD;
    float lv[16];
    float mx = -1e30f;
    #pragma unroll
    for (int j = 0; j < 4; ++j) {
        float4 x = *(const float4*)(row + j * 1024 + tid * 4);
        float4 c = *(const float4*)(cg + j * 1024 + tid * 4);
        lv[j * 4 + 0] = (x.x - c.x) * invT;
        lv[j * 4 + 1] = (x.y - c.y) * invT;
        lv[j * 4 + 2] = (x.z - c.z) * invT;
        lv[j * 4 + 3] = (x.w - c.w) * invT;
        mx = fmaxf(mx, fmaxf(fmaxf(lv[j * 4 + 0], lv[j * 4 + 1]), fmaxf(lv[j * 4 + 2], lv[j * 4 + 3])));
    }
    float m = bmax(mx, scr);
    float s = 0.f;
    #pragma unroll
    for (int i = 0; i < 16; ++i) s += __expf(lv[i] - m);
    float Z = bsum(s, scr);
    if (tid == 0) { ws[WS_TREG_M + r] = m; ws[WS_TREG_Z + r] = Z; }
}

// teacher fea inverse norms (12544 rows, 1 wave per row)
__global__ void k_tfea(const float* __restrict__ tfea, float* __restrict__ ws) {
    int wv = threadIdx.x >> 6, lane = threadIdx.x & 63;
    int r = blockIdx.x * 4 + wv;
    const float* row = tfea + (size_t)r * FEA;
    float s = 0.f;
    #pragma unroll
    for (int j = 0; j < 6; ++j) { float x = row[lane + 64 * j]; s += x * x; }
    #pragma unroll
    for (int m = 32; m >= 1; m >>= 1) s += __shfl_xor(s, m, 64);
    if (lane == 0) ws[WS_TFEA_INV + r] = 1.0f / fmaxf(sqrtf(s), 1e-12f);
}

// argmax over teacher cosine sim. grid: 1472 blocks (see decode)
__global__ void k_argmax(const float* __restrict__ sfea, const float* __restrict__ tfea,
                         const float* __restrict__ ws, int* __restrict__ ind) {
    __shared__ float sf[32][388];  // row stride 388 floats -> uniform bank spread
    int bid = blockIdx.x, tid = threadIdx.x;
    int crop, view, b, tile, S, off;
    if (bid < 448) {
        crop = (bid >= 224) ? 1 : 0;
        int rem = bid - crop * 224;
        view = 1 - crop;
        b = rem / 7; tile = rem % 7;
        S = NG; off = crop * 6272;
    } else {
        int r2 = bid - 448;
        crop = 2 + (r2 >> 7);
        int r3 = r2 & 127;
        view = r3 >> 6;
        int r4 = r3 & 63;
        b = r4 >> 1; tile = r4 & 1;
        S = NL; off = 12544 + (crop - 2) * 1152;
    }
    int row0 = off + b * S + tile * 32;
    int n_rows = min(32, S - tile * 32);

    float4 z4 = make_float4(0.f, 0.f, 0.f, 0.f);
    for (int i = tid; i < 32 * 97; i += 256) ((float4*)sf)[i] = z4;
    __syncthreads();
    for (int i = tid; i < n_rows * 96; i += 256) {
        int rr = i / 96, c = i % 96;
        float4 v = *(const float4*)(sfea + (size_t)(row0 + rr) * FEA + c * 4);
        *((float4*)&sf[rr][0] + c) = v;
    }
    __syncthreads();

    int s_local = tid >> 3, g8 = tid & 7;
    const float* tb = tfea + (size_t)(view * 6272 + b * 196) * FEA + g8 * 48;
    const float* tiv = ws + WS_TFEA_INV + view * 6272 + b * 196;
    const float4* sp = (const float4*)&sf[s_local][g8 * 48];

    float best = -1e30f; int bestn = 0;
    for (int n = 0; n < 196; n += 4) {
        const float* t0p = tb + (size_t)n * FEA;
        const float* t1p = t0p + FEA;
        const float* t2p = t1p + FEA;
        const float* t3p = t2p + FEA;
        float d0 = 0.f, d1 = 0.f, d2 = 0.f, d3 = 0.f;
        #pragma unroll
        for (int j = 0; j < 12; ++j) {
            float4 sv = sp[j];
            float4 t0 = *(const float4*)(t0p + j * 4);
            float4 t1 = *(const float4*)(t1p + j * 4);
            float4 t2 = *(const float4*)(t2p + j * 4);
            float4 t3 = *(const float4*)(t3p + j * 4);
            d0 += sv.x * t0.x + sv.y * t0.y + sv.z * t0.z + sv.w * t0.w;
            d1 += sv.x * t1.x + sv.y * t1.y + sv.z * t1.z + sv.w * t1.w;
            d2 += sv.x * t2.x + sv.y * t2.y + sv.z * t2.z + sv.w * t2.w;
            d3 += sv.x * t3.x + sv.y * t3.y + sv.z * t3.z + sv.w * t3.w;
        }
        d0 += __shfl_xor(d0, 1, 8); d0 += __shfl_xor(d0, 2, 8); d0 += __shfl_xor(d0, 4, 8);
        d1 += __shfl_xor(d1, 1, 8); d1 += __shfl_xor(d1, 2, 8); d1 += __shfl_xor(d1, 4, 8);
        d2 += __shfl_xor(d2, 1, 8); d2 += __shfl_xor(d2, 2, 8); d2 += __shfl_xor(d2, 4, 8);
        d3 += __shfl_xor(d3, 1, 8); d3 += __shfl_xor(d3, 2, 8); d3 += __shfl_xor(d3, 4, 8);
        if (g8 == 0) {
            float s0 = d0 * tiv[n];     if (s0 > best) { best = s0; bestn = n; }
            float s1 = d1 * tiv[n + 1]; if (s1 > best) { best = s1; bestn = n + 1; }
            float s2 = d2 * tiv[n + 2]; if (s2 > best) { best = s2; bestn = n + 2; }
            float s3 = d3 * tiv[n + 3]; if (s3 > best) { best = s3; bestn = n + 3; }
        }
    }
    if (g8 == 0 && s_local < n_rows) ind[(size_t)(row0 + s_local) * 2 + view] = bestn;
}

// region CE: one block per student region row (21760)
__global__ void k_region(const float* __restrict__ sreg, const float* __restrict__ treg,
                         const float* __restrict__ cgrid, const float* __restrict__ ws,
                         const int* __restrict__ ind, const int* __restrict__ ep,
                         float* __restrict__ acc) {
    __shared__ float scr[4];
    float invT = get_invT(ep);
    int r = blockIdx.x, tid = threadIdx.x;
    int crop, b;
    if (r < 6272) { crop = 0; b = r / 196; }
    else if (r < 12544) { crop = 1; b = (r - 6272) / 196; }
    else { int r2 = r - 12544; crop = 2 + r2 / 1152; int q = r2 % 1152; b = q / 36; }

    const float* srow = sreg + (size_t)r * KD;
    float sv[16], cgv[16];
    float mx = -1e30f;
    #pragma unroll
    for (int j = 0; j < 4; ++j) {
        float4 x = *(const float4*)(srow + j * 1024 + tid * 4);
        float4 c = *(const float4*)(cgrid + j * 1024 + tid * 4);
        sv[j * 4 + 0] = x.x; sv[j * 4 + 1] = x.y; sv[j * 4 + 2] = x.z; sv[j * 4 + 3] = x.w;
        cgv[j * 4 + 0] = c.x; cgv[j * 4 + 1] = c.y; cgv[j * 4 + 2] = c.z; cgv[j * 4 + 3] = c.w;
        mx = fmaxf(mx, fmaxf(fmaxf(x.x, x.y), fmaxf(x.z, x.w)));
    }
    float m10 = bmax(mx, scr) * 10.0f;
    float se = 0.f;
    #pragma unroll
    for (int i = 0; i < 16; ++i) se += __expf(sv[i] * 10.0f - m10);
    float Z = bsum(se, scr);
    float lse = m10 + __logf(Z);

    int v0 = (crop == 0) ? 1 : 0;
    int v1 = (crop >= 2) ? 1 : ((crop == 0) ? 1 : 0);
    for (int view = v0; view <= v1; ++view) {
        int id = ind[(size_t)r * 2 + view];
        int g = view * 6272 + b * 196 + id;
        const float* trow = treg + (size_t)g * KD;
        float tm = ws[WS_TREG_M + g];
        float tz = ws[WS_TREG_Z + g];
        float d = 0.f;
        #pragma unroll
        for (int j = 0; j < 4; ++j) {
            float4 t = *(const float4*)(trow + j * 1024 + tid * 4);
            d += __expf((t.x - cgv[j * 4 + 0]) * invT - tm) * sv[j * 4 + 0];
            d += __expf((t.y - cgv[j * 4 + 1]) * invT - tm) * sv[j * 4 + 1];
            d += __expf((t.z - cgv[j * 4 + 2]) * invT - tm) * sv[j * 4 + 2];
            d += __expf((t.w - cgv[j * 4 + 3]) * invT - tm) * sv[j * 4 + 3];
        }
        float D = bsum(d, scr);
        if (tid == 0) atomicAdd(&acc[view * 10 + crop], lse - INV_ST * (D / tz));
    }
}

// cls CE + L1: 18 pairs x 32 b
__global__ void k_cls(const float* __restrict__ scls, const float* __restrict__ ws,
                      float* __restrict__ acc) {
    __shared__ float scr[4];
    int p = blockIdx.x >> 5, b = blockIdx.x & 31, tid = threadIdx.x;
    int t = p / 9; int si = p % 9; int s = si + ((si >= t) ? 1 : 0);
    const float* tp = ws + WS_TCLS + (size_t)(t * BB + b) * KD;
    const float* sr = scls + (size_t)(s * BB + b) * KD;
    float svv[16], tv[16];
    float mx = -1e30f;
    #pragma unroll
    for (int j = 0; j < 4; ++j) {
        float4 x = *(const float4*)(sr + j * 1024 + tid * 4);
        float4 y = *(const float4*)(tp + j * 1024 + tid * 4);
        svv[j * 4 + 0] = x.x; svv[j * 4 + 1] = x.y; svv[j * 4 + 2] = x.z; svv[j * 4 + 3] = x.w;
        tv[j * 4 + 0] = y.x; tv[j * 4 + 1] = y.y; tv[j * 4 + 2] = y.z; tv[j * 4 + 3] = y.w;
        mx = fmaxf(mx, fmaxf(fmaxf(x.x, x.y), fmaxf(x.z, x.w)));
    }
    float m10 = bmax(mx, scr) * 10.0f;
    float se = 0.f, dp = 0.f, l1 = 0.f;
    #pragma unroll
    for (int i = 0; i < 16; ++i) {
        se += __expf(svv[i] * 10.0f - m10);
        dp += tv[i] * svv[i];
        l1 += fabsf(tv[i] - 10.0f * svv[i]);
    }
    float Z = bsum(se, scr);
    float lse = m10 + __logf(Z);
    float D = bsum(dp, scr);
    float L = bsum(l1, scr);
    if (tid == 0) {
        atomicAdd(&acc[20 + t * 10 + s], lse - 10.0f * D);
        atomicAdd(&acc[40 + t * 10 + s], L);
    }
}

__global__ void k_final(const float* __restrict__ acc, float* __restrict__ out) {
    if (threadIdx.x == 0 && blockIdx.x == 0) {
        float total = 0.f;
        for (int t = 0; t < 2; ++t)
            for (int s = 0; s < 10; ++s) {
                if (s == t) continue;
                int p = t * 10 + s;
                float Ssz = (s < 2) ? 196.0f : 36.0f;
                total += 0.5f * acc[20 + p] / 32.0f
                       + 0.005f * acc[40 + p] / (32.0f * 4096.0f)
                       + 0.5f * acc[p] / (32.0f * Ssz);
            }
        out[0] = total / 18.0f;
    }
}

extern "C" void kernel_launch(void* const* d_in, const int* in_sizes, int n_in,
                              void* d_out, int out_size, void* d_ws, size_t ws_size,
                              hipStream_t stream) {
    const float* scls = (const float*)d_in[0];
    const float* sreg = (const float*)d_in[1];
    const float* sfea = (const float*)d_in[2];
    const float* tcls = (const float*)d_in[3];
    const float* treg = (const float*)d_in[4];
    const float* tfea = (const float*)d_in[5];
    const float* center = (const float*)d_in[6];
    const float* cgrid = (const float*)d_in[7];
    const int* ep = (const int*)d_in[8];

    float* ws = (float*)d_ws;
    int* ind = (int*)(ws + WS_IND);
    float* acc = ws + WS_ACC;

    hipMemsetAsync(acc, 0, 64 * sizeof(float), stream);
    k_tcls<<<64, 256, 0, stream>>>(tcls, center, ep, ws);
    k_treg_stats<<<12544, 256, 0, stream>>>(treg, cgrid, ep, ws);
    k_tfea<<<3136, 256, 0, stream>>>(tfea, ws);
    k_argmax<<<1472, 256, 0, stream>>>(sfea, tfea, ws, ind);
    k_region<<<21760, 256, 0, stream>>>(sreg, treg, cgrid, ws, ind, ep, acc);
    k_cls<<<576, 256, 0, stream>>>(scls, ws, acc);
    k_final<<<1, 64, 0, stream>>>(acc, (float*)d_out);
}

// Round 2
// 1107.269 us; speedup vs baseline: 1.5526x; 1.5526x over previous
//
#include <hip/hip_runtime.h>
#include <math.h>

#define BB 32
#define KD 4096
#define FEA 384
#define NG 196
#define NL 36
#define INV_ST 10.0f

// ws layout (float index space)
#define WS_TCLS 0                           // 64*4096 teacher cls probs
#define WS_TREG_M (WS_TCLS + 64 * 4096)     // 12544 row max of (x-cg)/T
#define WS_TREG_Z (WS_TREG_M + 12544)       // 12544 row sum-exp
#define WS_TFEA_INV (WS_TREG_Z + 12544)     // 12544 teacher fea 1/norm
#define WS_IND (WS_TFEA_INV + 12544)        // 21760*2 int argmax indices
#define WS_ACC (WS_IND + 21760 * 2)         // 64 floats: [0..19] region, [20..39] cls CE, [40..59] L1

__device__ __forceinline__ float get_invT(const int* ep) {
    int e = *ep;
    float T = (e < 30) ? (0.04f + (float)e * (0.03f / 29.0f)) : 0.07f;
    return 1.0f / T;
}

__device__ __forceinline__ float bsum(float v, volatile float* scr) {
    #pragma unroll
    for (int m = 32; m >= 1; m >>= 1) v += __shfl_xor(v, m, 64);
    __syncthreads();
    if ((threadIdx.x & 63) == 0) scr[threadIdx.x >> 6] = v;
    __syncthreads();
    return scr[0] + scr[1] + scr[2] + scr[3];
}

__device__ __forceinline__ float bmax(float v, volatile float* scr) {
    #pragma unroll
    for (int m = 32; m >= 1; m >>= 1) v = fmaxf(v, __shfl_xor(v, m, 64));
    __syncthreads();
    if ((threadIdx.x & 63) == 0) scr[threadIdx.x >> 6] = v;
    __syncthreads();
    return fmaxf(fmaxf(scr[0], scr[1]), fmaxf(scr[2], scr[3]));
}

// teacher cls softmax probs -> ws  (64 rows)
__global__ void k_tcls(const float* __restrict__ tcls, const float* __restrict__ center,
                       const int* __restrict__ ep, float* __restrict__ ws) {
    __shared__ float scr[4];
    float invT = get_invT(ep);
    int r = blockIdx.x, tid = threadIdx.x;
    const float* row = tcls + (size_t)r * KD;
    float* out = ws + WS_TCLS + (size_t)r * KD;
    float lv[16];
    float mx = -1e30f;
    #pragma unroll
    for (int j = 0; j < 4; ++j) {
        float4 x = *(const float4*)(row + j * 1024 + tid * 4);
        float4 c = *(const float4*)(center + j * 1024 + tid * 4);
        lv[j * 4 + 0] = (x.x - c.x) * invT;
        lv[j * 4 + 1] = (x.y - c.y) * invT;
        lv[j * 4 + 2] = (x.z - c.z) * invT;
        lv[j * 4 + 3] = (x.w - c.w) * invT;
        mx = fmaxf(mx, fmaxf(fmaxf(lv[j * 4 + 0], lv[j * 4 + 1]), fmaxf(lv[j * 4 + 2], lv[j * 4 + 3])));
    }
    float m = bmax(mx, scr);
    float s = 0.f;
    #pragma unroll
    for (int i = 0; i < 16; ++i) s += __expf(lv[i] - m);
    float Z = bsum(s, scr);
    float iz = 1.0f / Z;
    #pragma unroll
    for (int j = 0; j < 4; ++j) {
        float4 o;
        o.x = __expf(lv[j * 4 + 0] - m) * iz;
        o.y = __expf(lv[j * 4 + 1] - m) * iz;
        o.z = __expf(lv[j * 4 + 2] - m) * iz;
        o.w = __expf(lv[j * 4 + 3] - m) * iz;
        *(float4*)(out + j * 1024 + tid * 4) = o;
    }
}

// teacher region softmax stats (m, Z) per row  (12544 rows)
__global__ void k_treg_stats(const float* __restrict__ treg, const float* __restrict__ cg,
                             const int* __restrict__ ep, float* __restrict__ ws) {
    __shared__ float scr[4];
    float invT = get_invT(ep);
    int r = blockIdx.x, tid = threadIdx.x;
    const float* row = treg + (size_t)r * KD;
    float lv[16];
    float mx = -1e30f;
    #pragma unroll
    for (int j = 0; j < 4; ++j) {
        float4 x = *(const float4*)(row + j * 1024 + tid * 4);
        float4 c = *(const float4*)(cg + j * 1024 + tid * 4);
        lv[j * 4 + 0] = (x.x - c.x) * invT;
        lv[j * 4 + 1] = (x.y - c.y) * invT;
        lv[j * 4 + 2] = (x.z - c.z) * invT;
        lv[j * 4 + 3] = (x.w - c.w) * invT;
        mx = fmaxf(mx, fmaxf(fmaxf(lv[j * 4 + 0], lv[j * 4 + 1]), fmaxf(lv[j * 4 + 2], lv[j * 4 + 3])));
    }
    float m = bmax(mx, scr);
    float s = 0.f;
    #pragma unroll
    for (int i = 0; i < 16; ++i) s += __expf(lv[i] - m);
    float Z = bsum(s, scr);
    if (tid == 0) { ws[WS_TREG_M + r] = m; ws[WS_TREG_Z + r] = Z; }
}

// teacher fea inverse norms (12544 rows, 1 wave per row)
__global__ void k_tfea(const float* __restrict__ tfea, float* __restrict__ ws) {
    int wv = threadIdx.x >> 6, lane = threadIdx.x & 63;
    int r = blockIdx.x * 4 + wv;
    const float* row = tfea + (size_t)r * FEA;
    float s = 0.f;
    #pragma unroll
    for (int j = 0; j < 6; ++j) { float x = row[lane + 64 * j]; s += x * x; }
    #pragma unroll
    for (int m = 32; m >= 1; m >>= 1) s += __shfl_xor(s, m, 64);
    if (lane == 0) ws[WS_TFEA_INV + r] = 1.0f / fmaxf(sqrtf(s), 1e-12f);
}

// argmax over teacher cosine sim, register-tiled fp32 GEMM.
// grid 832: [0,320): global crops (crop,b,5 tiles of 40 rows); [320,832): local (crop2,view,b) 36 rows.
// per block: sim[40][196] = S[40][384] x T[196][384]^T, argmax over n.
__global__ void k_argmax(const float* __restrict__ sfea, const float* __restrict__ tfea,
                         const float* __restrict__ ws, int* __restrict__ ind) {
    __shared__ float sA[40 * 64];    // linear; reads are wave-broadcast
    __shared__ float sB[128 * 64];   // float4-col xor-swizzled: c4' = c4 ^ ((row>>2)&7)
    int bid = blockIdx.x, tid = threadIdx.x;
    int row0, svalid, tb, view;
    if (bid < 320) {
        int crop = bid / 160; int rem = bid % 160; int b = rem / 5; int tile = rem % 5;
        view = 1 - crop;
        row0 = crop * 6272 + b * 196 + tile * 40;
        svalid = min(40, 196 - tile * 40);
        tb = view * 6272 + b * 196;
    } else {
        int r = bid - 320; int crop2 = r >> 6; int r2 = r & 63; view = r2 >> 5; int b = r2 & 31;
        row0 = 12544 + crop2 * 1152 + b * 36;
        svalid = 36;
        tb = view * 6272 + b * 196;
    }
    const float* tiv = ws + WS_TFEA_INV + tb;

    int si = tid >> 5, ni = tid & 31;
    float best[5]; int bestn[5];
    #pragma unroll
    for (int i = 0; i < 5; ++i) { best[i] = -1e30f; bestn[i] = 0; }
    float4 z4 = make_float4(0.f, 0.f, 0.f, 0.f);

    for (int nc = 0; nc < 2; ++nc) {
        int nbase = nc * 128;
        float acc[5][4];
        #pragma unroll
        for (int i = 0; i < 5; ++i)
            #pragma unroll
            for (int j = 0; j < 4; ++j) acc[i][j] = 0.f;

        for (int kb = 0; kb < 6; ++kb) {
            __syncthreads();
            // stage sA: 40 rows x 64 floats (640 float4)
            for (int i = tid; i < 640; i += 256) {
                int r = i >> 4, c = i & 15;
                float4 v = (r < svalid)
                    ? *(const float4*)(sfea + (size_t)(row0 + r) * FEA + kb * 64 + c * 4) : z4;
                *(float4*)(sA + r * 64 + c * 4) = v;
            }
            // stage sB: 128 teacher rows x 64 floats, swizzled (2048 float4)
            for (int i = tid; i < 2048; i += 256) {
                int r = i >> 4, c = i & 15;
                int n = nbase + r;
                float4 v = (n < 196)
                    ? *(const float4*)(tfea + (size_t)(tb + n) * FEA + kb * 64 + c * 4) : z4;
                int cs = c ^ ((r >> 2) & 7);
                *(float4*)(sB + r * 64 + cs * 4) = v;
            }
            __syncthreads();
            #pragma unroll 4
            for (int k4 = 0; k4 < 16; ++k4) {
                float4 a[5], bv[4];
                #pragma unroll
                for (int i = 0; i < 5; ++i)
                    a[i] = *(const float4*)(sA + (si * 5 + i) * 64 + k4 * 4);
                #pragma unroll
                for (int j = 0; j < 4; ++j) {
                    int r = ni * 4 + j;
                    bv[j] = *(const float4*)(sB + r * 64 + (k4 ^ ((r >> 2) & 7)) * 4);
                }
                #pragma unroll
                for (int i = 0; i < 5; ++i)
                    #pragma unroll
                    for (int j = 0; j < 4; ++j)
                        acc[i][j] += a[i].x * bv[j].x + a[i].y * bv[j].y
                                   + a[i].z * bv[j].z + a[i].w * bv[j].w;
            }
        }
        // fold this n-chunk into running best (first-max tie-break via strict >)
        #pragma unroll
        for (int j = 0; j < 4; ++j) {
            int n = nbase + ni * 4 + j;
            if (n < 196) {
                float iv = tiv[n];
                #pragma unroll
                for (int i = 0; i < 5; ++i) {
                    float s = acc[i][j] * iv;
                    if (s > best[i]) { best[i] = s; bestn[i] = n; }
                }
            }
        }
    }
    // reduce over the 32 ni lanes (width-32 groups = fixed si)
    #pragma unroll
    for (int m = 16; m >= 1; m >>= 1) {
        #pragma unroll
        for (int i = 0; i < 5; ++i) {
            float ob = __shfl_xor(best[i], m, 32);
            int on = __shfl_xor(bestn[i], m, 32);
            if (ob > best[i] || (ob == best[i] && on < bestn[i])) { best[i] = ob; bestn[i] = on; }
        }
    }
    if (ni == 0) {
        #pragma unroll
        for (int i = 0; i < 5; ++i) {
            int r = si * 5 + i;
            if (r < svalid) ind[(size_t)(row0 + r) * 2 + view] = bestn[i];
        }
    }
}

// region CE: one block per student region row (21760)
__global__ void k_region(const float* __restrict__ sreg, const float* __restrict__ treg,
                         const float* __restrict__ cgrid, const float* __restrict__ ws,
                         const int* __restrict__ ind, const int* __restrict__ ep,
                         float* __restrict__ acc) {
    __shared__ float scr[4];
    float invT = get_invT(ep);
    int r = blockIdx.x, tid = threadIdx.x;
    int crop, b;
    if (r < 6272) { crop = 0; b = r / 196; }
    else if (r < 12544) { crop = 1; b = (r - 6272) / 196; }
    else { int r2 = r - 12544; crop = 2 + r2 / 1152; int q = r2 % 1152; b = q / 36; }

    const float* srow = sreg + (size_t)r * KD;
    float sv[16], cgv[16];
    float mx = -1e30f;
    #pragma unroll
    for (int j = 0; j < 4; ++j) {
        float4 x = *(const float4*)(srow + j * 1024 + tid * 4);
        float4 c = *(const float4*)(cgrid + j * 1024 + tid * 4);
        sv[j * 4 + 0] = x.x; sv[j * 4 + 1] = x.y; sv[j * 4 + 2] = x.z; sv[j * 4 + 3] = x.w;
        cgv[j * 4 + 0] = c.x; cgv[j * 4 + 1] = c.y; cgv[j * 4 + 2] = c.z; cgv[j * 4 + 3] = c.w;
        mx = fmaxf(mx, fmaxf(fmaxf(x.x, x.y), fmaxf(x.z, x.w)));
    }
    float m10 = bmax(mx, scr) * 10.0f;
    float se = 0.f;
    #pragma unroll
    for (int i = 0; i < 16; ++i) se += __expf(sv[i] * 10.0f - m10);
    float Z = bsum(se, scr);
    float lse = m10 + __logf(Z);

    int v0 = (crop == 0) ? 1 : 0;
    int v1 = (crop >= 2) ? 1 : ((crop == 0) ? 1 : 0);
    for (int view = v0; view <= v1; ++view) {
        int id = ind[(size_t)r * 2 + view];
        int g = view * 6272 + b * 196 + id;
        const float* trow = treg + (size_t)g * KD;
        float tm = ws[WS_TREG_M + g];
        float tz = ws[WS_TREG_Z + g];
        float d = 0.f;
        #pragma unroll
        for (int j = 0; j < 4; ++j) {
            float4 t = *(const float4*)(trow + j * 1024 + tid * 4);
            d += __expf((t.x - cgv[j * 4 + 0]) * invT - tm) * sv[j * 4 + 0];
            d += __expf((t.y - cgv[j * 4 + 1]) * invT - tm) * sv[j * 4 + 1];
            d += __expf((t.z - cgv[j * 4 + 2]) * invT - tm) * sv[j * 4 + 2];
            d += __expf((t.w - cgv[j * 4 + 3]) * invT - tm) * sv[j * 4 + 3];
        }
        float D = bsum(d, scr);
        if (tid == 0) atomicAdd(&acc[view * 10 + crop], lse - INV_ST * (D / tz));
    }
}

// cls CE + L1: 18 pairs x 32 b
__global__ void k_cls(const float* __restrict__ scls, const float* __restrict__ ws,
                      float* __restrict__ acc) {
    __shared__ float scr[4];
    int p = blockIdx.x >> 5, b = blockIdx.x & 31, tid = threadIdx.x;
    int t = p / 9; int si = p % 9; int s = si + ((si >= t) ? 1 : 0);
    const float* tp = ws + WS_TCLS + (size_t)(t * BB + b) * KD;
    const float* sr = scls + (size_t)(s * BB + b) * KD;
    float svv[16], tv[16];
    float mx = -1e30f;
    #pragma unroll
    for (int j = 0; j < 4; ++j) {
        float4 x = *(const float4*)(sr + j * 1024 + tid * 4);
        float4 y = *(const float4*)(tp + j * 1024 + tid * 4);
        svv[j * 4 + 0] = x.x; svv[j * 4 + 1] = x.y; svv[j * 4 + 2] = x.z; svv[j * 4 + 3] = x.w;
        tv[j * 4 + 0] = y.x; tv[j * 4 + 1] = y.y; tv[j * 4 + 2] = y.z; tv[j * 4 + 3] = y.w;
        mx = fmaxf(mx, fmaxf(fmaxf(x.x, x.y), fmaxf(x.z, x.w)));
    }
    float m10 = bmax(mx, scr) * 10.0f;
    float se = 0.f, dp = 0.f, l1 = 0.f;
    #pragma unroll
    for (int i = 0; i < 16; ++i) {
        se += __expf(svv[i] * 10.0f - m10);
        dp += tv[i] * svv[i];
        l1 += fabsf(tv[i] - 10.0f * svv[i]);
    }
    float Z = bsum(se, scr);
    float lse = m10 + __logf(Z);
    float D = bsum(dp, scr);
    float L = bsum(l1, scr);
    if (tid == 0) {
        atomicAdd(&acc[20 + t * 10 + s], lse - 10.0f * D);
        atomicAdd(&acc[40 + t * 10 + s], L);
    }
}

__global__ void k_final(const float* __restrict__ acc, float* __restrict__ out) {
    if (threadIdx.x == 0 && blockIdx.x == 0) {
        float total = 0.f;
        for (int t = 0; t < 2; ++t)
            for (int s = 0; s < 10; ++s) {
                if (s == t) continue;
                int p = t * 10 + s;
                float Ssz = (s < 2) ? 196.0f : 36.0f;
                total += 0.5f * acc[20 + p] / 32.0f
                       + 0.005f * acc[40 + p] / (32.0f * 4096.0f)
                       + 0.5f * acc[p] / (32.0f * Ssz);
            }
        out[0] = total / 18.0f;
    }
}

extern "C" void kernel_launch(void* const* d_in, const int* in_sizes, int n_in,
                              void* d_out, int out_size, void* d_ws, size_t ws_size,
                              hipStream_t stream) {
    const float* scls = (const float*)d_in[0];
    const float* sreg = (const float*)d_in[1];
    const float* sfea = (const float*)d_in[2];
    const float* tcls = (const float*)d_in[3];
    const float* treg = (const float*)d_in[4];
    const float* tfea = (const float*)d_in[5];
    const float* center = (const float*)d_in[6];
    const float* cgrid = (const float*)d_in[7];
    const int* ep = (const int*)d_in[8];

    float* ws = (float*)d_ws;
    int* ind = (int*)(ws + WS_IND);
    float* acc = ws + WS_ACC;

    hipMemsetAsync(acc, 0, 64 * sizeof(float), stream);
    k_tcls<<<64, 256, 0, stream>>>(tcls, center, ep, ws);
    k_treg_stats<<<12544, 256, 0, stream>>>(treg, cgrid, ep, ws);
    k_tfea<<<3136, 256, 0, stream>>>(tfea, ws);
    k_argmax<<<832, 256, 0, stream>>>(sfea, tfea, ws, ind);
    k_region<<<21760, 256, 0, stream>>>(sreg, treg, cgrid, ws, ind, ep, acc);
    k_cls<<<576, 256, 0, stream>>>(scls, ws, acc);
    k_final<<<1, 64, 0, stream>>>(acc, (float*)d_out);
}